// Round 7
// baseline (48.609 us; speedup 1.0000x reference)
//
#include <hip/hip_runtime.h>
#include <hip/hip_cooperative_groups.h>

namespace cg = cooperative_groups;

#define BN_EPS 1e-5f

// Dependency cone of the single consumed output position (center voxel):
//   out(8,8,8) <- x2[15..17]^3 (64ch) <- x1[29..35]^3 (32ch) <- voxel[28..36]^3
// All interior; no padding logic.
//
// ONE cooperative launch, 128 blocks x 256 threads (all co-resident:
// 1 block/CU, 84 KB LDS, ~90 VGPR). R2/R6 showed ~10.8 us fixed cost per
// dispatch (3 kernels=32.5us, 2 kernels=21.5us, bodies only ~2-3us) -> fusing
// the two stages around a grid.sync() removes one fixed cost.
//
//   Phase A (blk = b*8+grp): conv1 recomputed per block (cheap) + conv2 for
//           8 co -> ws.x2[16][64][27]; grp0 seeds out[b][:] = bias.
//   grid.sync(): device-scope release/acquire makes ws visible cross-XCD.
//   Phase B (blk = b*8+grp): conv3 center for 16 co (110 KB w3 slice) + FC
//           partial via device-scope atomicAdd (order noise ~1e-6 << thr;
//           bias re-seeded every call -> graph replays idempotent).
//
// R4/R5 lesson kept: 256-thread blocks (1024-thr blocks pin VGPR=64 -> spill).
__global__ __launch_bounds__(256) void backbone_coop_kernel(
    const float* __restrict__ voxel, const float* __restrict__ w1,
    const float* __restrict__ g1, const float* __restrict__ b1,
    const float* __restrict__ m1, const float* __restrict__ v1,
    const float* __restrict__ w2, const float* __restrict__ g2,
    const float* __restrict__ b2, const float* __restrict__ m2,
    const float* __restrict__ v2, const float* __restrict__ w3,
    const float* __restrict__ g3, const float* __restrict__ b3,
    const float* __restrict__ m3, const float* __restrict__ v3,
    const float* __restrict__ wp, const float* __restrict__ bp,
    float* __restrict__ x2ws, float* __restrict__ out)
{
    const int b   = blockIdx.x >> 3;
    const int grp = blockIdx.x & 7;
    const int tid = threadIdx.x;

    __shared__ float s_in[729];                  // 9^3 input patch
    __shared__ float s_w1[864];                  // 32 x 27
    __shared__ __align__(16) float s_x1[10976];  // [343 pos][32 ci] channel-last
    __shared__ __align__(16) float s_w2[6912];   // [8 co][32 ci][27]
    __shared__ float sa1[32], ss1[32], sa2[8], ss2[8];
    __shared__ __align__(16) float s_x2[1728];   // phase B: [64 ci][27]
    __shared__ float s_x3[16];

    // ================= Phase A: conv1 (32 ch) + conv2 (8 co) ===============
    if (grp == 0) out[b * 256 + tid] = bp[tid];  // bias seed for FC atomics

    const float* vb = voxel + (size_t)b * 262144;
    for (int i = tid; i < 729; i += 256) {
        int z = i / 81, r = i % 81, y = r / 9, x = r % 9;
        s_in[i] = vb[(28 + z) * 4096 + (28 + y) * 64 + (28 + x)];
    }
    for (int i = tid; i < 864; i += 256) s_w1[i] = w1[i];
    {   // w2 slice for this group, coalesced float4
        const float4* src = (const float4*)(w2 + (size_t)grp * 8 * 32 * 27);
        float4* dst = (float4*)s_w2;
        for (int i = tid; i < 1728; i += 256) dst[i] = src[i];
    }
    if (tid < 32) {
        float a = g1[tid] * rsqrtf(v1[tid] + BN_EPS);
        sa1[tid] = a; ss1[tid] = b1[tid] - m1[tid] * a;
    } else if (tid < 40) {
        int c = grp * 8 + (tid - 32);
        float a = g2[c] * rsqrtf(v2[c] + BN_EPS);
        sa2[tid - 32] = a; ss2[tid - 32] = b2[c] - m2[c] * a;
    }
    __syncthreads();

    // ---- conv1 (stride 1) + BN + ReLU -> s_x1[pos][co] ----
    // Thread = (co = tid&31, row-group rg = tid>>5); row task (z,y) computes
    // 7 x-outputs from 9 row registers. s_in reads broadcast across 32 co.
    {
        const int co = tid & 31, rg = tid >> 5;
        float wc[27];
        #pragma unroll
        for (int k = 0; k < 27; ++k) wc[k] = s_w1[co * 27 + k];
        const float a = sa1[co], sh = ss1[co];
        for (int r = rg; r < 49; r += 8) {        // r = z*7 + y
            const int z = r / 7, y = r % 7;
            float acc[7];
            #pragma unroll
            for (int x = 0; x < 7; ++x) acc[x] = 0.f;
            #pragma unroll
            for (int kd = 0; kd < 3; ++kd)
            #pragma unroll
            for (int kh = 0; kh < 3; ++kh) {
                float row[9];
                #pragma unroll
                for (int x = 0; x < 9; ++x)
                    row[x] = s_in[(z + kd) * 81 + (y + kh) * 9 + x];
                #pragma unroll
                for (int kw = 0; kw < 3; ++kw) {
                    const float w = wc[kd * 9 + kh * 3 + kw];
                    #pragma unroll
                    for (int x = 0; x < 7; ++x)
                        acc[x] += row[x + kw] * w;
                }
            }
            #pragma unroll
            for (int x = 0; x < 7; ++x)           // banks 0..31 per x - clean
                s_x1[(r * 7 + x) * 32 + co] = fmaxf(acc[x] * a + sh, 0.f);
        }
    }
    __syncthreads();

    // ---- conv2 (stride 2) + BN + ReLU -> x2ws[b][co][27] ----
    // Thread = (col = tid>>5, ci = tid&31). Weight LDS->reg reads: lane
    // stride 27, gcd(27,32)=1 -> conflict-free. Activation reads: bank = ci.
    {
        const int col = tid >> 5, ci = tid & 31;
        float wr[27];
        const float* wl = s_w2 + (col * 32 + ci) * 27;
        #pragma unroll
        for (int k = 0; k < 27; ++k) wr[k] = wl[k];
        float p[27];
        #pragma unroll
        for (int q = 0; q < 27; ++q) p[q] = 0.f;

        for (int z = 0; z < 7; ++z)
        for (int y = 0; y < 7; ++y) {             // uniform loops
            float row[7];
            #pragma unroll
            for (int x = 0; x < 7; ++x)
                row[x] = s_x1[((z * 7 + y) * 7 + x) * 32 + ci];
            #pragma unroll
            for (int i = 0; i < 3; ++i) {
                const int kd = z - 2 * i;
                if (kd < 0 || kd > 2) continue;   // uniform branch
                #pragma unroll
                for (int jj = 0; jj < 3; ++jj) {
                    const int kh = y - 2 * jj;
                    if (kh < 0 || kh > 2) continue;
                    #pragma unroll
                    for (int k = 0; k < 3; ++k)
                    #pragma unroll
                    for (int kw = 0; kw < 3; ++kw)
                        p[i * 9 + jj * 3 + k] += row[2 * k + kw]
                                               * wr[kd * 9 + kh * 3 + kw];
                }
            }
        }

        #pragma unroll
        for (int q = 0; q < 27; ++q) {            // reduce over 32 ci lanes
            p[q] += __shfl_xor(p[q], 1);
            p[q] += __shfl_xor(p[q], 2);
            p[q] += __shfl_xor(p[q], 4);
            p[q] += __shfl_xor(p[q], 8);
            p[q] += __shfl_xor(p[q], 16);
        }
        float val = 0.f;
        #pragma unroll
        for (int q = 0; q < 27; ++q)              // compile-time indices only
            if (ci == q) val = p[q];
        if (ci < 27) {
            const int co = grp * 8 + col;
            x2ws[((size_t)b * 64 + co) * 27 + ci] =
                fmaxf(val * sa2[col] + ss2[col], 0.f);
        }
    }

    // ================= grid-wide barrier ===================================
    cg::this_grid().sync();

    // ================= Phase B: conv3 center (16 co) + FC partial ==========
    {
        const float4* src = (const float4*)(x2ws + (size_t)b * 1728);
        float4* dst = (float4*)s_x2;
        for (int i = tid; i < 432; i += 256) dst[i] = src[i];
    }
    __syncthreads();

    {   // conv3: 16-lane group per co; coalesced float4 over w3 row.
        const int col = tid >> 4, j = tid & 15;
        const int co = grp * 16 + col;
        const float4* wv = (const float4*)(w3 + (size_t)co * 1728);
        const float4* xv = (const float4*)s_x2;
        float acc = 0.f;
        #pragma unroll
        for (int t = 0; t < 27; ++t) {
            float4 w4 = wv[j + 16 * t];
            float4 x4 = xv[j + 16 * t];
            acc += w4.x * x4.x + w4.y * x4.y + w4.z * x4.z + w4.w * x4.w;
        }
        acc += __shfl_xor(acc, 1);
        acc += __shfl_xor(acc, 2);
        acc += __shfl_xor(acc, 4);
        acc += __shfl_xor(acc, 8);
        if (j == 0) {
            float a = g3[co] * rsqrtf(v3[co] + BN_EPS);
            float s = b3[co] - m3[co] * a;
            s_x3[col] = fmaxf(acc * a + s, 0.f);
        }
    }
    __syncthreads();

    {   // FC partial over this group's 16 channels; wp coalesced (lane = f).
        float facc = 0.f;
        #pragma unroll
        for (int c = 0; c < 16; ++c)
            facc += s_x3[c] * wp[(grp * 16 + c) * 256 + tid];
        atomicAdd(&out[b * 256 + tid], facc);
    }
}

extern "C" void kernel_launch(void* const* d_in, const int* in_sizes, int n_in,
                              void* d_out, int out_size, void* d_ws, size_t ws_size,
                              hipStream_t stream) {
    const float* voxel = (const float*)d_in[0];
    const float* w1 = (const float*)d_in[1];
    const float* g1 = (const float*)d_in[2];
    const float* b1 = (const float*)d_in[3];
    const float* m1 = (const float*)d_in[4];
    const float* v1 = (const float*)d_in[5];
    const float* w2 = (const float*)d_in[6];
    const float* g2 = (const float*)d_in[7];
    const float* b2 = (const float*)d_in[8];
    const float* m2 = (const float*)d_in[9];
    const float* v2 = (const float*)d_in[10];
    const float* w3 = (const float*)d_in[11];
    const float* g3 = (const float*)d_in[12];
    const float* b3 = (const float*)d_in[13];
    const float* m3 = (const float*)d_in[14];
    const float* v3 = (const float*)d_in[15];
    const float* wp = (const float*)d_in[16];
    const float* bp = (const float*)d_in[17];
    float* out = (float*)d_out;
    float* ws_x2 = (float*)d_ws;                 // [16][64][27] floats

    void* args[] = {
        (void*)&voxel, (void*)&w1, (void*)&g1, (void*)&b1, (void*)&m1,
        (void*)&v1, (void*)&w2, (void*)&g2, (void*)&b2, (void*)&m2,
        (void*)&v2, (void*)&w3, (void*)&g3, (void*)&b3, (void*)&m3,
        (void*)&v3, (void*)&wp, (void*)&bp, (void*)&ws_x2, (void*)&out
    };
    hipLaunchCooperativeKernel((void*)backbone_coop_kernel,
                               dim3(128), dim3(256), args, 0, stream);
}

// Round 8
// 32.835 us; speedup vs baseline: 1.4804x; 1.4804x over previous
//
#include <hip/hip_runtime.h>

#define BN_EPS 1e-5f

// Dependency cone of the single consumed output position (center voxel):
//   out(8,8,8) <- x2[15..17]^3 (64ch) <- x1[29..35]^3 (32ch) <- voxel[28..36]^3
// All interior; no padding logic.
//
// ONE worker kernel (128 blocks = 16 batch x 8 ci/co-groups, 256 thr) plus a
// 64-byte hipMemsetAsync that zeroes the arrival counters each call.
//
// Per block (b,g):
//   conv1 (all 32 ch, replicated per block - cheap) -> s_x1 LDS
//   conv2 (8 co slice)                              -> s_x2f LDS [8ci*27]
//   conv3-PARTIAL: its 8 x2-channels x all 128 co3 (w3 slice 110 KB,
//       contiguous 216-float rows)                  -> part[blk][128] (global)
//   __syncthreads; tid0: __threadfence(release); old=atomicAdd(&cnt[b],1)
//   if old==7 (wait-free finisher, last arriver):
//       __threadfence(acquire); sum 8 partials in FIXED g-order
//       (deterministic fp), BN+ReLU -> s_x3; FC -> out[b][:]
//
// Replay-safe: cnt zeroed by the memset node every call; part[] is
// write-then-read within one call (no init needed); out fully rewritten.
// R4/R5 lesson: 256-thread blocks (1024-thr pins VGPR=64 -> spill).
// R7 lesson: cooperative grid.sync costs +27 us; classic dispatch only.
__global__ __launch_bounds__(256) void backbone_finisher_kernel(
    const float* __restrict__ voxel, const float* __restrict__ w1,
    const float* __restrict__ g1, const float* __restrict__ b1,
    const float* __restrict__ m1, const float* __restrict__ v1,
    const float* __restrict__ w2, const float* __restrict__ g2,
    const float* __restrict__ b2, const float* __restrict__ m2,
    const float* __restrict__ v2, const float* __restrict__ w3,
    const float* __restrict__ g3, const float* __restrict__ b3,
    const float* __restrict__ m3, const float* __restrict__ v3,
    const float* __restrict__ wp, const float* __restrict__ bp,
    float* __restrict__ part, int* __restrict__ cnt,
    float* __restrict__ out)
{
    const int b   = blockIdx.x >> 3;
    const int g   = blockIdx.x & 7;
    const int tid = threadIdx.x;

    __shared__ float s_in[729];                  // 9^3 input patch
    __shared__ float s_w1[864];                  // 32 x 27
    __shared__ __align__(16) float s_x1[10976];  // [343 pos][32 ci] channel-last
    __shared__ __align__(16) float s_w2[6912];   // [8 co][32 ci][27]
    __shared__ float s_x2f[216];                 // conv2 out: [8 ci][27] contiguous
    __shared__ float s_x3[128];                  // finisher: BN+ReLU(conv3)
    __shared__ float sa1[32], ss1[32], sa2[8], ss2[8];
    __shared__ int   s_flag;

    // ---- Phase 0: stage input patch + weights + folded BN consts ----
    const float* vb = voxel + (size_t)b * 262144;
    for (int i = tid; i < 729; i += 256) {
        int z = i / 81, r = i % 81, y = r / 9, x = r % 9;
        s_in[i] = vb[(28 + z) * 4096 + (28 + y) * 64 + (28 + x)];
    }
    for (int i = tid; i < 864; i += 256) s_w1[i] = w1[i];
    {   // w2 slice for this group, coalesced float4
        const float4* src = (const float4*)(w2 + (size_t)g * 8 * 32 * 27);
        float4* dst = (float4*)s_w2;
        for (int i = tid; i < 1728; i += 256) dst[i] = src[i];
    }
    if (tid < 32) {
        float a = g1[tid] * rsqrtf(v1[tid] + BN_EPS);
        sa1[tid] = a; ss1[tid] = b1[tid] - m1[tid] * a;
    } else if (tid < 40) {
        int c = g * 8 + (tid - 32);
        float a = g2[c] * rsqrtf(v2[c] + BN_EPS);
        sa2[tid - 32] = a; ss2[tid - 32] = b2[c] - m2[c] * a;
    }
    __syncthreads();

    // ---- conv1 (stride 1) + BN + ReLU -> s_x1[pos][co] ----
    // Thread = (co = tid&31, row-group rg = tid>>5); row task (z,y) computes
    // 7 x-outputs from 9 row registers. s_in reads broadcast across 32 co.
    {
        const int co = tid & 31, rg = tid >> 5;
        float wc[27];
        #pragma unroll
        for (int k = 0; k < 27; ++k) wc[k] = s_w1[co * 27 + k];
        const float a = sa1[co], sh = ss1[co];
        for (int r = rg; r < 49; r += 8) {        // r = z*7 + y
            const int z = r / 7, y = r % 7;
            float acc[7];
            #pragma unroll
            for (int x = 0; x < 7; ++x) acc[x] = 0.f;
            #pragma unroll
            for (int kd = 0; kd < 3; ++kd)
            #pragma unroll
            for (int kh = 0; kh < 3; ++kh) {
                float row[9];
                #pragma unroll
                for (int x = 0; x < 9; ++x)
                    row[x] = s_in[(z + kd) * 81 + (y + kh) * 9 + x];
                #pragma unroll
                for (int kw = 0; kw < 3; ++kw) {
                    const float w = wc[kd * 9 + kh * 3 + kw];
                    #pragma unroll
                    for (int x = 0; x < 7; ++x)
                        acc[x] += row[x + kw] * w;
                }
            }
            #pragma unroll
            for (int x = 0; x < 7; ++x)           // banks 0..31 per x - clean
                s_x1[(r * 7 + x) * 32 + co] = fmaxf(acc[x] * a + sh, 0.f);
        }
    }
    __syncthreads();

    // ---- conv2 (stride 2) + BN + ReLU -> s_x2f[col*27 + pos] ----
    // Thread = (col = tid>>5, ci = tid&31). Weight LDS->reg: lane stride 27,
    // gcd(27,32)=1 -> conflict-free. Activation reads: bank = ci, clean.
    {
        const int col = tid >> 5, ci = tid & 31;
        float wr[27];
        const float* wl = s_w2 + (col * 32 + ci) * 27;
        #pragma unroll
        for (int k = 0; k < 27; ++k) wr[k] = wl[k];
        float p[27];
        #pragma unroll
        for (int q = 0; q < 27; ++q) p[q] = 0.f;

        for (int z = 0; z < 7; ++z)
        for (int y = 0; y < 7; ++y) {             // uniform loops
            float row[7];
            #pragma unroll
            for (int x = 0; x < 7; ++x)
                row[x] = s_x1[((z * 7 + y) * 7 + x) * 32 + ci];
            #pragma unroll
            for (int i = 0; i < 3; ++i) {
                const int kd = z - 2 * i;
                if (kd < 0 || kd > 2) continue;   // uniform branch
                #pragma unroll
                for (int jj = 0; jj < 3; ++jj) {
                    const int kh = y - 2 * jj;
                    if (kh < 0 || kh > 2) continue;
                    #pragma unroll
                    for (int k = 0; k < 3; ++k)
                    #pragma unroll
                    for (int kw = 0; kw < 3; ++kw)
                        p[i * 9 + jj * 3 + k] += row[2 * k + kw]
                                               * wr[kd * 9 + kh * 3 + kw];
                }
            }
        }

        #pragma unroll
        for (int q = 0; q < 27; ++q) {            // reduce over 32 ci lanes
            p[q] += __shfl_xor(p[q], 1);
            p[q] += __shfl_xor(p[q], 2);
            p[q] += __shfl_xor(p[q], 4);
            p[q] += __shfl_xor(p[q], 8);
            p[q] += __shfl_xor(p[q], 16);
        }
        float val = 0.f;
        #pragma unroll
        for (int q = 0; q < 27; ++q)              // compile-time indices only
            if (ci == q) val = p[q];
        if (ci < 27)                               // s_x2f[ci-slice][pos]
            s_x2f[col * 27 + ci] = fmaxf(val * sa2[col] + ss2[col], 0.f);
    }
    __syncthreads();

    // ---- conv3 PARTIAL over this block's 8 ci -> part[blk][128] ----
    // 16 lane-groups of 16; each group does 8 co3. For fixed co3, the
    // (8 ci x 27) w3 slice is CONTIGUOUS (216 floats at w3+co3*1728+g*216)
    // and matches s_x2f's layout exactly -> coalesced global + clean LDS.
    {
        const int gi = tid >> 4, j = tid & 15;
        #pragma unroll
        for (int cc = 0; cc < 8; ++cc) {
            const int co3 = gi * 8 + cc;
            const float* wrow = w3 + (size_t)co3 * 1728 + g * 216;
            float acc = 0.f;
            #pragma unroll
            for (int t = 0; t < 14; ++t) {
                const int idx = j + 16 * t;
                if (idx < 216)                     // 216 = 16*13 + 8
                    acc += wrow[idx] * s_x2f[idx];
            }
            acc += __shfl_xor(acc, 1);
            acc += __shfl_xor(acc, 2);
            acc += __shfl_xor(acc, 4);
            acc += __shfl_xor(acc, 8);
            if (j == 0)
                part[(size_t)blockIdx.x * 128 + co3] = acc;
        }
    }
    __syncthreads();                               // drains part[] stores

    // ---- arrival + wait-free finisher ----
    if (tid == 0) {
        __threadfence();                           // release part[] writes
        s_flag = atomicAdd(&cnt[b], 1);            // device-scope
    }
    __syncthreads();
    if (s_flag == 7) {                             // last arriver for batch b
        __threadfence();                           // acquire others' part[]
        if (tid < 128) {
            const int co3 = tid;
            float s = 0.f;
            #pragma unroll
            for (int gg = 0; gg < 8; ++gg)         // fixed order: deterministic
                s += part[(size_t)(b * 8 + gg) * 128 + co3];
            float a = g3[co3] * rsqrtf(v3[co3] + BN_EPS);
            float sh = b3[co3] - m3[co3] * a;
            s_x3[co3] = fmaxf(s * a + sh, 0.f);
        }
        __syncthreads();
        // FC: lane = feature (coalesced wp); 128 LDS broadcasts.
        float acc = bp[tid];
        for (int c = 0; c < 128; ++c)
            acc += s_x3[c] * wp[c * 256 + tid];
        out[b * 256 + tid] = acc;
    }
}

extern "C" void kernel_launch(void* const* d_in, const int* in_sizes, int n_in,
                              void* d_out, int out_size, void* d_ws, size_t ws_size,
                              hipStream_t stream) {
    const float* voxel = (const float*)d_in[0];
    const float* w1 = (const float*)d_in[1];
    const float* g1 = (const float*)d_in[2];
    const float* b1 = (const float*)d_in[3];
    const float* m1 = (const float*)d_in[4];
    const float* v1 = (const float*)d_in[5];
    const float* w2 = (const float*)d_in[6];
    const float* g2 = (const float*)d_in[7];
    const float* b2 = (const float*)d_in[8];
    const float* m2 = (const float*)d_in[9];
    const float* v2 = (const float*)d_in[10];
    const float* w3 = (const float*)d_in[11];
    const float* g3 = (const float*)d_in[12];
    const float* b3 = (const float*)d_in[13];
    const float* m3 = (const float*)d_in[14];
    const float* v3 = (const float*)d_in[15];
    const float* wp = (const float*)d_in[16];
    const float* bp = (const float*)d_in[17];
    float* out = (float*)d_out;

    float* part = (float*)d_ws;                    // [128][128] floats = 64 KB
    int*   cnt  = (int*)((char*)d_ws + 128 * 128 * sizeof(float));  // 16 ints

    hipMemsetAsync(cnt, 0, 16 * sizeof(int), stream);   // graph-capturable
    backbone_finisher_kernel<<<128, 256, 0, stream>>>(
        voxel, w1, g1, b1, m1, v1, w2, g2, b2, m2, v2,
        w3, g3, b3, m3, v3, wp, bp, part, cnt, out);
}